// Round 9
// baseline (321.058 us; speedup 1.0000x reference)
//
#include <hip/hip_runtime.h>
#include <math.h>

typedef unsigned short u16;
typedef unsigned int u32;
typedef __bf16 bf16x8_t __attribute__((ext_vector_type(8)));
typedef float f32x4_t __attribute__((ext_vector_type(4)));

__device__ __forceinline__ u16 f2bf(float f) {
  __bf16 b = (__bf16)f;
  return __builtin_bit_cast(u16, b);
}

__device__ __forceinline__ void gld16(const void* g, void* l) {
  __builtin_amdgcn_global_load_lds(
      (const __attribute__((address_space(1))) void*)g,
      (__attribute__((address_space(3))) void*)l, 16, 0, 0);
}

// tanh-form GELU via rcp: gelu = v - v*rcp(e^{2z}+1). Correct limits at +/-inf.
__device__ __forceinline__ float gelu_f(float v) {
  float z = 0.7978845608028654f * v * fmaf(0.044715f, v * v, 1.0f);
  float t = __builtin_amdgcn_exp2f(2.8853900817779268f * z);   // e^{2z}
  float r = __builtin_amdgcn_rcpf(t + 1.0f);
  return v - v * r;
}

__device__ __forceinline__ int swz8(int bid, int nwg) {
  int cpx = nwg >> 3;                 // requires nwg % 8 == 0
  return (bid & 7) * cpx + (bid >> 3);
}

// ---------------------------------------------------------------------------
// cast fp32 -> bf16 (w1)
__global__ __launch_bounds__(256) void cast_kernel(const float* __restrict__ src,
                                                   u16* __restrict__ dst, int n) {
  int i = (blockIdx.x * 256 + threadIdx.x) * 4;
  if (i < n) {
    float4 v = *(const float4*)(src + i);
    uint2 o;
    o.x = (u32)f2bf(v.x) | ((u32)f2bf(v.y) << 16);
    o.y = (u32)f2bf(v.z) | ((u32)f2bf(v.w) << 16);
    *(uint2*)(dst + i) = o;
  }
}

// ---------------------------------------------------------------------------
// b2ob[c] = b2[c] + sum_i grn_b[i]*w2[c][i]
__global__ __launch_bounds__(64) void b2ob_kernel(const float* __restrict__ w2,
                                                  const float* __restrict__ grn_b,
                                                  const float* __restrict__ b2,
                                                  float* __restrict__ out) {
  int c = blockIdx.x;
  int l = threadIdx.x;
  float p = 0.f;
  for (int i = l; i < 1536; i += 64) p += grn_b[i] * w2[(size_t)c * 1536 + i];
  #pragma unroll
  for (int s = 32; s; s >>= 1) p += __shfl_xor(p, s);
  if (l == 0) out[c] = b2[c] + p;
}

// ---------------------------------------------------------------------------
// depthwise conv (K=7, pad 3) + LayerNorm over C, output bf16 [B*T][512]
__global__ __launch_bounds__(512, 4) void conv_ln_kernel(const float* __restrict__ X,
                                                         const float* __restrict__ Wd,
                                                         const float* __restrict__ bd,
                                                         const float* __restrict__ lng,
                                                         const float* __restrict__ lnb,
                                                         u16* __restrict__ Y) {
  __shared__ float ystage[16 * 516];
  __shared__ float mu_s[16], rs_s[16];

  const int c = threadIdx.x;
  const int b = blockIdx.y;
  const int t0 = blockIdx.x * 64;

  const float* xr = X + ((size_t)b * 512 + c) * 2048;
  float wr[7];
  #pragma unroll
  for (int k = 0; k < 7; ++k) wr[k] = Wd[c * 7 + k];
  const float bdv = bd[c];
  const float lg = lng[c];
  const float lb = lnb[c];

  for (int ch = 0; ch < 4; ++ch) {
    const int tc0 = t0 + ch * 16;
    const int g = tc0 - 4;
    float w[24];
    if (g >= 0 && g + 24 <= 2048) {
      #pragma unroll
      for (int q = 0; q < 6; ++q) {
        float4 v = *(const float4*)(xr + g + q * 4);
        w[q * 4 + 0] = v.x; w[q * 4 + 1] = v.y;
        w[q * 4 + 2] = v.z; w[q * 4 + 3] = v.w;
      }
    } else {
      #pragma unroll
      for (int j = 0; j < 24; ++j) {
        int tt = g + j;
        w[j] = (tt >= 0 && tt < 2048) ? xr[tt] : 0.f;
      }
    }
    float outv[16];
    #pragma unroll
    for (int i = 0; i < 16; ++i) {
      float a = bdv;
      #pragma unroll
      for (int k = 0; k < 7; ++k) a = fmaf(w[i + 1 + k], wr[k], a);
      outv[i] = a;
      ystage[i * 516 + c] = a;
    }
    __syncthreads();
    {
      int r = c >> 5, cl = c & 31;
      float s = 0.f, q = 0.f;
      #pragma unroll
      for (int k = 0; k < 16; ++k) {
        float v = ystage[r * 516 + cl + k * 32];
        s += v; q += v * v;
      }
      #pragma unroll
      for (int m = 16; m; m >>= 1) { s += __shfl_xor(s, m); q += __shfl_xor(q, m); }
      if (cl == 0) {
        float mu = s * (1.f / 512.f);
        float var = q * (1.f / 512.f) - mu * mu;
        mu_s[r] = mu;
        rs_s[r] = rsqrtf(var + 1e-6f);
      }
    }
    __syncthreads();
    #pragma unroll
    for (int i = 0; i < 16; ++i) {
      float v = (outv[i] - mu_s[i]) * rs_s[i] * lg + lb;
      Y[(size_t)(b * 2048 + tc0 + i) * 512 + c] = f2bf(v);
    }
  }
}

// ---------------------------------------------------------------------------
// GRN scale: s[b][i] = 1 + grn_g[i]*gx/(mean(gx)+1e-6)
__global__ __launch_bounds__(256) void grn_kernel(const float* __restrict__ gsum,
                                                  const float* __restrict__ grn_g,
                                                  float* __restrict__ svec) {
  __shared__ float red[256];
  int b = blockIdx.x, tid = threadIdx.x;
  float gx[6];
  float part = 0.f;
  #pragma unroll
  for (int it = 0; it < 6; ++it) {
    int i = it * 256 + tid;
    gx[it] = sqrtf(gsum[b * 1536 + i]);
    part += gx[it];
  }
  red[tid] = part;
  __syncthreads();
  for (int s = 128; s; s >>= 1) {
    if (tid < s) red[tid] += red[tid + s];
    __syncthreads();
  }
  float inv = 1.0f / (red[0] * (1.f / 1536.f) + 1e-6f);
  #pragma unroll
  for (int it = 0; it < 6; ++it) {
    int i = it * 256 + tid;
    svec[b * 1536 + i] = 1.0f + grn_g[i] * gx[it] * inv;
  }
}

// ---------------------------------------------------------------------------
// w2s[b][c][i] = bf16( w2[c][i] * svec[b][i] )
__global__ __launch_bounds__(256) void w2s_kernel(const float* __restrict__ w2,
                                                  const float* __restrict__ svec,
                                                  u16* __restrict__ out) {
  size_t e0 = ((size_t)blockIdx.x * 256 + threadIdx.x) * 8;  // flat into [16][512][1536]
  int i = (int)(e0 % 1536);
  size_t bc = e0 / 1536;
  int b = (int)(bc >> 9);
  size_t widx = (bc & 511) * 1536 + i;
  float4 wa = *(const float4*)(w2 + widx);
  float4 wb = *(const float4*)(w2 + widx + 4);
  float4 sa = *(const float4*)(svec + b * 1536 + i);
  float4 sb = *(const float4*)(svec + b * 1536 + i + 4);
  uint4 o;
  o.x = (u32)f2bf(wa.x * sa.x) | ((u32)f2bf(wa.y * sa.y) << 16);
  o.y = (u32)f2bf(wa.z * sa.z) | ((u32)f2bf(wa.w * sa.w) << 16);
  o.z = (u32)f2bf(wb.x * sb.x) | ((u32)f2bf(wb.y * sb.y) << 16);
  o.w = (u32)f2bf(wb.z * sb.z) | ((u32)f2bf(wb.w * sb.w) << 16);
  *(uint4*)(out + e0) = o;
}

// ---------------------------------------------------------------------------
// 128x128-tile K-loop, A-DIRECT variant:
//  - A fragments load straight global->VGPR (MFMA A-layout == row-major slices:
//    one bf16x8 per lane, 16 rows x 64B per instr; kk=0/1 pair covers exactly
//    one 128B line per row -> zero overfetch; wn-dup wave hits L1).
//    Double-buffered in registers (aP/aQ, statically indexed via step-pair).
//  - B staged via gld16, XOR-swizzled, 2-phase double-buffer (2 x 16KB LDS).
//  LDS traffic/step drops 96KB -> 48KB; A has no barrier dependency at all.
//  Step: STAGE_B(S+1) ; LOAD_A(S+1) ; ds_read B(S) ; MFMA(aCur) ; barrier.
//  Race-safety: buf[cur^1] last read at S-1 before that step's barrier; aN is
//  a distinct reg array from aC; barrier's vmcnt drain covers B completion.
template<int KD>
__device__ __forceinline__ void gemm_kloop(const u16* __restrict__ Ag,
                                           const u16* __restrict__ Bg,
                                           u16* lds, int NT,
                                           f32x4_t (&acc)[4][4]) {
  const int tid = threadIdx.x;
  const int l = tid & 63, l15 = l & 15, lq = l >> 4;
  const int w = tid >> 6;                         // 0..3
  const int wm = w >> 1, wn = w & 1;
  const int rin = tid >> 3;                       // 0..31
  const int cs = ((tid & 7) ^ (rin & 7)) << 3;    // pre-swizzled k-chunk (u16)

  const u16* Aw = Ag + (size_t)(wm * 64 + l15) * KD + lq * 8;  // wave's A base

  auto STAGE_B = [&](int buf, int kt) {
    u16* lB = lds + buf * 8192;
    #pragma unroll
    for (int c = 0; c < 4; ++c)
      gld16(Bg + (size_t)(c * 32 + rin) * KD + kt + cs, lB + (c * 32 + w * 8) * 64);
  };
  auto LOAD_A = [&](bf16x8_t (&ar)[4][2], int kt) {
    #pragma unroll
    for (int f = 0; f < 4; ++f)
      #pragma unroll
      for (int kk = 0; kk < 2; ++kk)
        ar[f][kk] = *(const bf16x8_t*)(Aw + (size_t)(f * 16) * KD + kt + kk * 32);
  };

  bf16x8_t aP[4][2], aQ[4][2];
  STAGE_B(0, 0);
  LOAD_A(aP, 0);
  __syncthreads();

  auto STEP = [&](int S, int cur, bf16x8_t (&aC)[4][2], bf16x8_t (&aN)[4][2]) {
    const bool pf = (S + 1 < NT);
    if (pf) {
      STAGE_B(cur ^ 1, (S + 1) * 64);
      LOAD_A(aN, (S + 1) * 64);
    }
    u16* lB = lds + cur * 8192;
    bf16x8_t bf[4][2];
    #pragma unroll
    for (int g = 0; g < 4; ++g) {
      const int Rb = wn * 64 + g * 16 + l15;
      #pragma unroll
      for (int kk = 0; kk < 2; ++kk)
        bf[g][kk] = *(const bf16x8_t*)(lB + Rb * 64 + (((kk * 4 + lq) ^ (Rb & 7)) << 3));
    }
    #pragma unroll
    for (int i = 0; i < 4; ++i)
      #pragma unroll
      for (int j = 0; j < 4; ++j)
        #pragma unroll
        for (int kk = 0; kk < 2; ++kk)
          acc[i][j] = __builtin_amdgcn_mfma_f32_16x16x32_bf16(aC[i][kk], bf[j][kk], acc[i][j], 0, 0, 0);
    __syncthreads();
  };

  for (int S = 0; S < NT; S += 2) {   // NT is even (8 or 24)
    STEP(S, 0, aP, aQ);
    STEP(S + 1, 1, aQ, aP);
  }
}

// ---------------------------------------------------------------------------
// GEMM1: h = gelu(y_ln . w1^T + b1), M=32768 K=512 N=1536; + gsum col sumsq
__global__ __launch_bounds__(256, 2) void gemm1_kernel(const u16* __restrict__ A,
                                                       const u16* __restrict__ Bw,
                                                       const float* __restrict__ b1,
                                                       u16* __restrict__ H,
                                                       float* __restrict__ gsum) {
  extern __shared__ __align__(16) u16 lds[];   // 32KB kloop B-dbuf; epi overlays 128x130 u16
  const int tid = threadIdx.x;
  const int l = tid & 63, l15 = l & 15, lq = l >> 4;
  const int w = tid >> 6, wm = w >> 1, wn = w & 1;
  const int wg = swz8(blockIdx.x, 3072);
  const int ntile = wg % 12, mtile = wg / 12;   // consecutive wg share A-panel
  const int m0 = mtile * 128, n0 = ntile * 128;
  const int bidx = m0 >> 11;

  f32x4_t acc[4][4];
  #pragma unroll
  for (int i = 0; i < 4; ++i)
    #pragma unroll
    for (int j = 0; j < 4; ++j) {
      f32x4_t z = {0.f, 0.f, 0.f, 0.f};
      acc[i][j] = z;
    }

  gemm_kloop<512>(A + (size_t)m0 * 512, Bw + (size_t)n0 * 512, lds, 8, acc);

  float bj[4];
  #pragma unroll
  for (int nf = 0; nf < 4; ++nf) bj[nf] = b1[n0 + wn * 64 + nf * 16 + l15];

  float ss[4] = {0.f, 0.f, 0.f, 0.f};
  #pragma unroll
  for (int mf = 0; mf < 4; ++mf) {
    const int lr = wm * 64 + mf * 16 + lq * 4;
    #pragma unroll
    for (int nf = 0; nf < 4; ++nf) {
      const int cl = wn * 64 + nf * 16 + l15;
      #pragma unroll
      for (int r = 0; r < 4; ++r) {
        float g = gelu_f(acc[mf][nf][r] + bj[nf]);
        ss[nf] += g * g;
        lds[(lr + r) * 130 + cl] = f2bf(g);
      }
    }
  }
  #pragma unroll
  for (int nf = 0; nf < 4; ++nf) {
    float v = ss[nf];
    v += __shfl_xor(v, 16);
    v += __shfl_xor(v, 32);
    if (lq == 0) atomicAdd(&gsum[bidx * 1536 + n0 + wn * 64 + nf * 16 + l15], v);
  }
  __syncthreads();
  #pragma unroll
  for (int it = 0; it < 8; ++it) {
    int idx = it * 256 + tid;      // 0..2047 = 128 rows x 16 chunks
    int row = idx >> 4, ch = idx & 15;
    uint4 v = *(const uint4*)(lds + row * 130 + ch * 8);
    *(uint4*)(H + (size_t)(m0 + row) * 1536 + n0 + ch * 8) = v;
  }
}

// ---------------------------------------------------------------------------
// GEMM2: out[b][c][t] = x + h . w2s(b)^T + b2ob[c], M=32768 K=1536 N=512
__global__ __launch_bounds__(256, 2) void gemm2_kernel(const u16* __restrict__ Hm,
                                                       const u16* __restrict__ W2s,
                                                       const float* __restrict__ b2ob,
                                                       const float* __restrict__ X,
                                                       float* __restrict__ Out) {
  extern __shared__ __align__(16) u16 lds[];   // 32KB kloop; epi overlays [64][129] f32
  const int tid = threadIdx.x;
  const int l = tid & 63, l15 = l & 15, lq = l >> 4;
  const int w = tid >> 6, wm = w >> 1, wn = w & 1;
  const int wg = swz8(blockIdx.x, 1024);
  const int ntile = wg & 3, mtile = wg >> 2;
  const int m0 = mtile * 128, n0 = ntile * 128;
  const int bidx = m0 >> 11, t0 = m0 & 2047;

  f32x4_t acc[4][4];
  #pragma unroll
  for (int i = 0; i < 4; ++i)
    #pragma unroll
    for (int j = 0; j < 4; ++j) {
      f32x4_t z = {0.f, 0.f, 0.f, 0.f};
      acc[i][j] = z;
    }

  gemm_kloop<1536>(Hm + (size_t)m0 * 1536,
                   W2s + ((size_t)bidx * 512 + n0) * 1536, lds, 24, acc);

  // transpose epilogue: 2 halves of 64 t-rows; f32 stage [64][129] conflict-free
  float* st = (float*)lds;
  for (int half = 0; half < 2; ++half) {
    __syncthreads();
    if (wm == half) {
      #pragma unroll
      for (int mf = 0; mf < 4; ++mf) {
        const int lr = mf * 16 + lq * 4;
        #pragma unroll
        for (int nf = 0; nf < 4; ++nf) {
          const int cl = wn * 64 + nf * 16 + l15;
          #pragma unroll
          for (int r = 0; r < 4; ++r)
            st[(lr + r) * 129 + cl] = acc[mf][nf][r];
        }
      }
    }
    __syncthreads();
    const size_t obase = ((size_t)bidx * 512 + n0) * 2048 + (size_t)(t0 + half * 64 + l);
    #pragma unroll
    for (int cc = 0; cc < 32; ++cc) {
      const int c = w * 32 + cc;
      float v = st[l * 129 + c] + b2ob[n0 + c];
      size_t oi = obase + (size_t)c * 2048;
      Out[oi] = v + X[oi];
    }
  }
}

// ---------------------------------------------------------------------------
extern "C" void kernel_launch(void* const* d_in, const int* in_sizes, int n_in,
                              void* d_out, int out_size, void* d_ws, size_t ws_size,
                              hipStream_t stream) {
  const float* x     = (const float*)d_in[0];
  const float* dw_w  = (const float*)d_in[1];
  const float* dw_b  = (const float*)d_in[2];
  const float* ln_g  = (const float*)d_in[3];
  const float* ln_b  = (const float*)d_in[4];
  const float* w1    = (const float*)d_in[5];
  const float* b1    = (const float*)d_in[6];
  const float* grn_g = (const float*)d_in[7];
  const float* grn_b = (const float*)d_in[8];
  const float* w2    = (const float*)d_in[9];
  const float* b2    = (const float*)d_in[10];
  float* out = (float*)d_out;

  // workspace layout (w2s overlays y_ln: y_ln is dead after gemm1)
  u16* y_ln = (u16*)d_ws;                             // 32768*512 u16
  u16* w2s  = y_ln;                                   // 16*512*1536 u16
  u16* h    = y_ln + (size_t)32768 * 512;             // 32768*1536 u16
  u16* w1b  = h + (size_t)32768 * 1536;               // 1536*512 u16
  float* gsum = (float*)(w1b + (size_t)1536 * 512);   // 16*1536 f32
  float* svec = gsum + 16 * 1536;                     // 16*1536 f32
  float* b2ob = svec + 16 * 1536;                     // 512 f32

  (void)hipFuncSetAttribute((const void*)gemm1_kernel,
                            hipFuncAttributeMaxDynamicSharedMemorySize, 33536);
  (void)hipFuncSetAttribute((const void*)gemm2_kernel,
                            hipFuncAttributeMaxDynamicSharedMemorySize, 33536);

  hipMemsetAsync(gsum, 0, 16 * 1536 * sizeof(float), stream);
  cast_kernel<<<768, 256, 0, stream>>>(w1, w1b, 1536 * 512);
  b2ob_kernel<<<512, 64, 0, stream>>>(w2, grn_b, b2, b2ob);
  conv_ln_kernel<<<dim3(32, 16), 512, 0, stream>>>(x, dw_w, dw_b, ln_g, ln_b, y_ln);
  gemm1_kernel<<<3072, 256, 33536, stream>>>(y_ln, w1b, b1, h, gsum);
  grn_kernel<<<16, 256, 0, stream>>>(gsum, grn_g, svec);
  w2s_kernel<<<6144, 256, 0, stream>>>(w2, svec, w2s);
  gemm2_kernel<<<1024, 256, 33536, stream>>>(h, w2s, b2ob, x, out);
}

// Round 10
// 239.651 us; speedup vs baseline: 1.3397x; 1.3397x over previous
//
#include <hip/hip_runtime.h>
#include <math.h>

typedef unsigned short u16;
typedef unsigned int u32;
typedef __bf16 bf16x8_t __attribute__((ext_vector_type(8)));
typedef float f32x4_t __attribute__((ext_vector_type(4)));

#define MEMF() asm volatile("" ::: "memory")
__device__ __forceinline__ void bar() {
  MEMF();
  __builtin_amdgcn_s_barrier();
  MEMF();
}

__device__ __forceinline__ u16 f2bf(float f) {
  __bf16 b = (__bf16)f;
  return __builtin_bit_cast(u16, b);
}

__device__ __forceinline__ void gld16(const void* g, void* l) {
  __builtin_amdgcn_global_load_lds(
      (const __attribute__((address_space(1))) void*)g,
      (__attribute__((address_space(3))) void*)l, 16, 0, 0);
}

// tanh-form GELU via rcp: gelu = v - v*rcp(e^{2z}+1). Correct limits at +/-inf.
__device__ __forceinline__ float gelu_f(float v) {
  float z = 0.7978845608028654f * v * fmaf(0.044715f, v * v, 1.0f);
  float t = __builtin_amdgcn_exp2f(2.8853900817779268f * z);   // e^{2z}
  float r = __builtin_amdgcn_rcpf(t + 1.0f);
  return v - v * r;
}

__device__ __forceinline__ int swz8(int bid, int nwg) {
  int cpx = nwg >> 3;                 // requires nwg % 8 == 0
  return (bid & 7) * cpx + (bid >> 3);
}

// ---------------------------------------------------------------------------
// cast fp32 -> bf16 (w1)
__global__ __launch_bounds__(256) void cast_kernel(const float* __restrict__ src,
                                                   u16* __restrict__ dst, int n) {
  int i = (blockIdx.x * 256 + threadIdx.x) * 4;
  if (i < n) {
    float4 v = *(const float4*)(src + i);
    uint2 o;
    o.x = (u32)f2bf(v.x) | ((u32)f2bf(v.y) << 16);
    o.y = (u32)f2bf(v.z) | ((u32)f2bf(v.w) << 16);
    *(uint2*)(dst + i) = o;
  }
}

// ---------------------------------------------------------------------------
// b2ob[c] = b2[c] + sum_i grn_b[i]*w2[c][i]
__global__ __launch_bounds__(64) void b2ob_kernel(const float* __restrict__ w2,
                                                  const float* __restrict__ grn_b,
                                                  const float* __restrict__ b2,
                                                  float* __restrict__ out) {
  int c = blockIdx.x;
  int l = threadIdx.x;
  float p = 0.f;
  for (int i = l; i < 1536; i += 64) p += grn_b[i] * w2[(size_t)c * 1536 + i];
  #pragma unroll
  for (int s = 32; s; s >>= 1) p += __shfl_xor(p, s);
  if (l == 0) out[c] = b2[c] + p;
}

// ---------------------------------------------------------------------------
// depthwise conv (K=7, pad 3) + LayerNorm over C, output bf16 [B*T][512]
__global__ __launch_bounds__(512, 4) void conv_ln_kernel(const float* __restrict__ X,
                                                         const float* __restrict__ Wd,
                                                         const float* __restrict__ bd,
                                                         const float* __restrict__ lng,
                                                         const float* __restrict__ lnb,
                                                         u16* __restrict__ Y) {
  __shared__ float ystage[16 * 516];
  __shared__ float mu_s[16], rs_s[16];

  const int c = threadIdx.x;
  const int b = blockIdx.y;
  const int t0 = blockIdx.x * 64;

  const float* xr = X + ((size_t)b * 512 + c) * 2048;
  float wr[7];
  #pragma unroll
  for (int k = 0; k < 7; ++k) wr[k] = Wd[c * 7 + k];
  const float bdv = bd[c];
  const float lg = lng[c];
  const float lb = lnb[c];

  for (int ch = 0; ch < 4; ++ch) {
    const int tc0 = t0 + ch * 16;
    const int g = tc0 - 4;
    float w[24];
    if (g >= 0 && g + 24 <= 2048) {
      #pragma unroll
      for (int q = 0; q < 6; ++q) {
        float4 v = *(const float4*)(xr + g + q * 4);
        w[q * 4 + 0] = v.x; w[q * 4 + 1] = v.y;
        w[q * 4 + 2] = v.z; w[q * 4 + 3] = v.w;
      }
    } else {
      #pragma unroll
      for (int j = 0; j < 24; ++j) {
        int tt = g + j;
        w[j] = (tt >= 0 && tt < 2048) ? xr[tt] : 0.f;
      }
    }
    float outv[16];
    #pragma unroll
    for (int i = 0; i < 16; ++i) {
      float a = bdv;
      #pragma unroll
      for (int k = 0; k < 7; ++k) a = fmaf(w[i + 1 + k], wr[k], a);
      outv[i] = a;
      ystage[i * 516 + c] = a;
    }
    __syncthreads();
    {
      int r = c >> 5, cl = c & 31;
      float s = 0.f, q = 0.f;
      #pragma unroll
      for (int k = 0; k < 16; ++k) {
        float v = ystage[r * 516 + cl + k * 32];
        s += v; q += v * v;
      }
      #pragma unroll
      for (int m = 16; m; m >>= 1) { s += __shfl_xor(s, m); q += __shfl_xor(q, m); }
      if (cl == 0) {
        float mu = s * (1.f / 512.f);
        float var = q * (1.f / 512.f) - mu * mu;
        mu_s[r] = mu;
        rs_s[r] = rsqrtf(var + 1e-6f);
      }
    }
    __syncthreads();
    #pragma unroll
    for (int i = 0; i < 16; ++i) {
      float v = (outv[i] - mu_s[i]) * rs_s[i] * lg + lb;
      Y[(size_t)(b * 2048 + tc0 + i) * 512 + c] = f2bf(v);
    }
  }
}

// ---------------------------------------------------------------------------
// GRN scale: s[b][i] = 1 + grn_g[i]*gx/(mean(gx)+1e-6)
__global__ __launch_bounds__(256) void grn_kernel(const float* __restrict__ gsum,
                                                  const float* __restrict__ grn_g,
                                                  float* __restrict__ svec) {
  __shared__ float red[256];
  int b = blockIdx.x, tid = threadIdx.x;
  float gx[6];
  float part = 0.f;
  #pragma unroll
  for (int it = 0; it < 6; ++it) {
    int i = it * 256 + tid;
    gx[it] = sqrtf(gsum[b * 1536 + i]);
    part += gx[it];
  }
  red[tid] = part;
  __syncthreads();
  for (int s = 128; s; s >>= 1) {
    if (tid < s) red[tid] += red[tid + s];
    __syncthreads();
  }
  float inv = 1.0f / (red[0] * (1.f / 1536.f) + 1e-6f);
  #pragma unroll
  for (int it = 0; it < 6; ++it) {
    int i = it * 256 + tid;
    svec[b * 1536 + i] = 1.0f + grn_g[i] * gx[it] * inv;
  }
}

// ---------------------------------------------------------------------------
// w2s[b][c][i] = bf16( w2[c][i] * svec[b][i] )
__global__ __launch_bounds__(256) void w2s_kernel(const float* __restrict__ w2,
                                                  const float* __restrict__ svec,
                                                  u16* __restrict__ out) {
  size_t e0 = ((size_t)blockIdx.x * 256 + threadIdx.x) * 8;  // flat into [16][512][1536]
  int i = (int)(e0 % 1536);
  size_t bc = e0 / 1536;
  int b = (int)(bc >> 9);
  size_t widx = (bc & 511) * 1536 + i;
  float4 wa = *(const float4*)(w2 + widx);
  float4 wb = *(const float4*)(w2 + widx + 4);
  float4 sa = *(const float4*)(svec + b * 1536 + i);
  float4 sb = *(const float4*)(svec + b * 1536 + i + 4);
  uint4 o;
  o.x = (u32)f2bf(wa.x * sa.x) | ((u32)f2bf(wa.y * sa.y) << 16);
  o.y = (u32)f2bf(wa.z * sa.z) | ((u32)f2bf(wa.w * sa.w) << 16);
  o.z = (u32)f2bf(wb.x * sb.x) | ((u32)f2bf(wb.y * sb.y) << 16);
  o.w = (u32)f2bf(wb.z * sb.z) | ((u32)f2bf(wb.w * sb.w) << 16);
  *(uint4*)(out + e0) = o;
}

// ---------------------------------------------------------------------------
// 256x128-tile K-loop, TRIPLE-buffered with counted vmcnt (T4):
//   512 threads, 8 waves as 4M x 2N; per-wave output 64x64 (acc[4][4]).
//   Buffers: 3 x (A 256x64 32KB + B 128x64 16KB) = 144KB LDS, 1 block/CU.
//   Step S (buf = S%3): issue STAGE(S+2 -> (S+2)%3) [6 gld16];
//     ds_read buf; 32 MFMA/wave; s_waitcnt vmcnt(6); s_barrier.
//   vmcnt(6) waits for STAGE(S+1) (oldest in flight) while STAGE(S+2)'s 6
//   loads stay in flight across the barrier -> each stage has ~2 full steps
//   of in-flight time (> HBM latency). Never drains to 0 in the main loop.
//   Ledger: overwrite target (S+2)%3 was last ds_read in step S-1; all those
//   reads are in regs (lgkm) before step S-1's barrier -> safe. Read buffer
//   S%3 was staged in step S-2 and confirmed landed by step S-1's
//   vmcnt(6)+barrier (vmcnt completes oldest-first, m135).
//   Tail: S+2>=NT -> no stage; wait vmcnt(0) at S=NT-2; none at NT-1.
//   XOR-swizzle via pre-swizzled global source + swizzled ds_read (0-conflict
//   scheme verified in R5).
template<int KD>
__device__ __forceinline__ void gemm_kloop(const u16* __restrict__ Ag,
                                           const u16* __restrict__ Bg,
                                           u16* lds, int NT,
                                           f32x4_t (&acc)[4][4]) {
  const int tid = threadIdx.x;
  const int l = tid & 63, l15 = l & 15, lq = l >> 4;
  const int w = tid >> 6;                         // 0..7
  const int wm = w >> 1, wn = w & 1;
  const int rin = tid >> 3;                       // 0..63
  const int cs = ((tid & 7) ^ (rin & 7)) << 3;    // pre-swizzled k-chunk (u16)
  const int wb = w * 512;                         // wave LDS offset (u16)

  auto STAGE = [&](int buf, int kt) {
    u16* lA = lds + buf * 24576;
    u16* lB = lA + 16384;
    #pragma unroll
    for (int c = 0; c < 4; ++c)        // A: 256 rows
      gld16(Ag + (size_t)(c * 64 + rin) * KD + kt + cs, lA + c * 4096 + wb);
    #pragma unroll
    for (int c = 0; c < 2; ++c)        // B: 128 rows
      gld16(Bg + (size_t)(c * 64 + rin) * KD + kt + cs, lB + c * 4096 + wb);
  };

  // prologue: stage tiles 0 and 1; ensure tile0 landed (6 newest still fly)
  STAGE(0, 0);
  STAGE(1, 64);
  asm volatile("s_waitcnt vmcnt(6)" ::: "memory");
  bar();

  int bufS = 0;
  for (int S = 0; S < NT; ++S) {
    if (S + 2 < NT) {
      int bn = bufS + 2; if (bn >= 3) bn -= 3;
      STAGE(bn, (S + 2) * 64);
    }
    u16* lA = lds + bufS * 24576;
    u16* lB = lA + 16384;
    bf16x8_t af[4][2], bfr[4][2];
    #pragma unroll
    for (int f = 0; f < 4; ++f) {
      const int Ra = wm * 64 + f * 16 + l15;
      #pragma unroll
      for (int kk = 0; kk < 2; ++kk)
        af[f][kk] = *(const bf16x8_t*)(lA + Ra * 64 + (((kk * 4 + lq) ^ (Ra & 7)) << 3));
    }
    #pragma unroll
    for (int g = 0; g < 4; ++g) {
      const int Rb = wn * 64 + g * 16 + l15;
      #pragma unroll
      for (int kk = 0; kk < 2; ++kk)
        bfr[g][kk] = *(const bf16x8_t*)(lB + Rb * 64 + (((kk * 4 + lq) ^ (Rb & 7)) << 3));
    }
    #pragma unroll
    for (int i = 0; i < 4; ++i)
      #pragma unroll
      for (int j = 0; j < 4; ++j)
        #pragma unroll
        for (int kk = 0; kk < 2; ++kk)
          acc[i][j] = __builtin_amdgcn_mfma_f32_16x16x32_bf16(af[i][kk], bfr[j][kk], acc[i][j], 0, 0, 0);
    if (S + 2 < NT)      { asm volatile("s_waitcnt vmcnt(6)" ::: "memory"); }
    else if (S + 1 < NT) { asm volatile("s_waitcnt vmcnt(0)" ::: "memory"); }
    bar();
    bufS = (bufS == 2) ? 0 : bufS + 1;
  }
}

// ---------------------------------------------------------------------------
// GEMM1: h = gelu(y_ln . w1^T + b1), M=32768 K=512 N=1536; + gsum col sumsq
__global__ __launch_bounds__(512, 2) void gemm1_kernel(const u16* __restrict__ A,
                                                       const u16* __restrict__ Bw,
                                                       const float* __restrict__ b1,
                                                       u16* __restrict__ H,
                                                       float* __restrict__ gsum) {
  extern __shared__ __align__(16) u16 lds[];   // 144KB kloop; epi overlays 256x130 u16
  const int tid = threadIdx.x;
  const int l = tid & 63, l15 = l & 15, lq = l >> 4;
  const int w = tid >> 6, wm = w >> 1, wn = w & 1;
  const int wg = swz8(blockIdx.x, 1536);
  const int ntile = wg % 12, mtile = wg / 12;   // consecutive wg share A-panel
  const int m0 = mtile * 256, n0 = ntile * 128;
  const int bidx = m0 >> 11;

  f32x4_t acc[4][4];
  #pragma unroll
  for (int i = 0; i < 4; ++i)
    #pragma unroll
    for (int j = 0; j < 4; ++j) {
      f32x4_t z = {0.f, 0.f, 0.f, 0.f};
      acc[i][j] = z;
    }

  gemm_kloop<512>(A + (size_t)m0 * 512, Bw + (size_t)n0 * 512, lds, 8, acc);

  float bj[4];
  #pragma unroll
  for (int nf = 0; nf < 4; ++nf) bj[nf] = b1[n0 + wn * 64 + nf * 16 + l15];

  // each wave owns a disjoint 64x64 quadrant of the 256x128 stage -> no gate
  float ss[4] = {0.f, 0.f, 0.f, 0.f};
  #pragma unroll
  for (int mf = 0; mf < 4; ++mf) {
    const int lr = wm * 64 + mf * 16 + lq * 4;
    #pragma unroll
    for (int nf = 0; nf < 4; ++nf) {
      const int cl = wn * 64 + nf * 16 + l15;
      #pragma unroll
      for (int r = 0; r < 4; ++r) {
        float g = gelu_f(acc[mf][nf][r] + bj[nf]);
        ss[nf] += g * g;
        lds[(lr + r) * 130 + cl] = f2bf(g);
      }
    }
  }
  #pragma unroll
  for (int nf = 0; nf < 4; ++nf) {
    float v = ss[nf];
    v += __shfl_xor(v, 16);
    v += __shfl_xor(v, 32);
    if (lq == 0) atomicAdd(&gsum[bidx * 1536 + n0 + wn * 64 + nf * 16 + l15], v);
  }
  __syncthreads();
  #pragma unroll
  for (int it = 0; it < 8; ++it) {
    int idx = it * 512 + tid;      // 0..4095 = 256 rows x 16 chunks
    int row = idx >> 4, ch = idx & 15;
    uint4 v = *(const uint4*)(lds + row * 130 + ch * 8);
    *(uint4*)(H + (size_t)(m0 + row) * 1536 + n0 + ch * 8) = v;
  }
}

// ---------------------------------------------------------------------------
// GEMM2: out[b][c][t] = x + h . w2s(b)^T + b2ob[c], M=32768 K=1536 N=512
__global__ __launch_bounds__(512, 2) void gemm2_kernel(const u16* __restrict__ Hm,
                                                       const u16* __restrict__ W2s,
                                                       const float* __restrict__ b2ob,
                                                       const float* __restrict__ X,
                                                       float* __restrict__ Out) {
  extern __shared__ __align__(16) u16 lds[];   // 144KB kloop; epi overlays [64][129] f32
  const int tid = threadIdx.x;
  const int l = tid & 63, l15 = l & 15, lq = l >> 4;
  const int w = tid >> 6, wm = w >> 1, wn = w & 1;
  const int wg = swz8(blockIdx.x, 512);
  const int ntile = wg & 3, mtile = wg >> 2;
  const int m0 = mtile * 256, n0 = ntile * 128;
  const int bidx = m0 >> 11, t0 = m0 & 2047;

  f32x4_t acc[4][4];
  #pragma unroll
  for (int i = 0; i < 4; ++i)
    #pragma unroll
    for (int j = 0; j < 4; ++j) {
      f32x4_t z = {0.f, 0.f, 0.f, 0.f};
      acc[i][j] = z;
    }

  gemm_kloop<1536>(Hm + (size_t)m0 * 1536,
                   W2s + ((size_t)bidx * 512 + n0) * 1536, lds, 24, acc);

  // transpose epilogue: 4 groups of 64 t-rows; f32 stage [64][129] conflict-free
  float* st = (float*)lds;
  for (int grp = 0; grp < 4; ++grp) {
    __syncthreads();
    if (wm == grp) {
      #pragma unroll
      for (int mf = 0; mf < 4; ++mf) {
        const int lr = mf * 16 + lq * 4;
        #pragma unroll
        for (int nf = 0; nf < 4; ++nf) {
          const int cl = wn * 64 + nf * 16 + l15;
          #pragma unroll
          for (int r = 0; r < 4; ++r)
            st[(lr + r) * 129 + cl] = acc[mf][nf][r];
        }
      }
    }
    __syncthreads();
    const size_t obase = ((size_t)bidx * 512 + n0) * 2048 + (size_t)(t0 + grp * 64 + l);
    #pragma unroll
    for (int cc = 0; cc < 16; ++cc) {
      const int c = w * 16 + cc;
      float v = st[l * 129 + c] + b2ob[n0 + c];
      size_t oi = obase + (size_t)c * 2048;
      Out[oi] = v + X[oi];
    }
  }
}

// ---------------------------------------------------------------------------
extern "C" void kernel_launch(void* const* d_in, const int* in_sizes, int n_in,
                              void* d_out, int out_size, void* d_ws, size_t ws_size,
                              hipStream_t stream) {
  const float* x     = (const float*)d_in[0];
  const float* dw_w  = (const float*)d_in[1];
  const float* dw_b  = (const float*)d_in[2];
  const float* ln_g  = (const float*)d_in[3];
  const float* ln_b  = (const float*)d_in[4];
  const float* w1    = (const float*)d_in[5];
  const float* b1    = (const float*)d_in[6];
  const float* grn_g = (const float*)d_in[7];
  const float* grn_b = (const float*)d_in[8];
  const float* w2    = (const float*)d_in[9];
  const float* b2    = (const float*)d_in[10];
  float* out = (float*)d_out;

  // workspace layout (w2s overlays y_ln: y_ln is dead after gemm1)
  u16* y_ln = (u16*)d_ws;                             // 32768*512 u16
  u16* w2s  = y_ln;                                   // 16*512*1536 u16
  u16* h    = y_ln + (size_t)32768 * 512;             // 32768*1536 u16
  u16* w1b  = h + (size_t)32768 * 1536;               // 1536*512 u16
  float* gsum = (float*)(w1b + (size_t)1536 * 512);   // 16*1536 f32
  float* svec = gsum + 16 * 1536;                     // 16*1536 f32
  float* b2ob = svec + 16 * 1536;                     // 512 f32

  (void)hipFuncSetAttribute((const void*)gemm1_kernel,
                            hipFuncAttributeMaxDynamicSharedMemorySize, 147456);
  (void)hipFuncSetAttribute((const void*)gemm2_kernel,
                            hipFuncAttributeMaxDynamicSharedMemorySize, 147456);

  hipMemsetAsync(gsum, 0, 16 * 1536 * sizeof(float), stream);
  cast_kernel<<<768, 256, 0, stream>>>(w1, w1b, 1536 * 512);
  b2ob_kernel<<<512, 64, 0, stream>>>(w2, grn_b, b2, b2ob);
  conv_ln_kernel<<<dim3(32, 16), 512, 0, stream>>>(x, dw_w, dw_b, ln_g, ln_b, y_ln);
  gemm1_kernel<<<1536, 512, 147456, stream>>>(y_ln, w1b, b1, h, gsum);
  grn_kernel<<<16, 256, 0, stream>>>(gsum, grn_g, svec);
  w2s_kernel<<<6144, 256, 0, stream>>>(w2, svec, w2s);
  gemm2_kernel<<<512, 512, 147456, stream>>>(h, w2s, b2ob, x, out);
}